// Round 7
// baseline (5594.656 us; speedup 1.0000x reference)
//
#include <hip/hip_runtime.h>
#include <hip/hip_fp16.h>
#include <float.h>

typedef _Float16 f16x8 __attribute__((ext_vector_type(8)));
typedef float f32x4 __attribute__((ext_vector_type(4)));

#define N_PTS 65536
#define D_DIM 512
#define K_EMB 4096

// ---------- screen geometry ----------
#define FBM 256            // rows per block
#define FBN 256            // cols per chunk
#define NCH 16             // K_EMB / FBN
#define NDS 16             // D_DIM / 32
#define NT  256            // NCH * NDS steps
#define TILE_HB 16384      // 16KB per hi-tile (256 rows x 32 halves)
#define CAP 8000000u       // candidate buffer entries

#define GLOAD16(gsrc, ldst)                                                    \
  __builtin_amdgcn_global_load_lds(                                            \
      (const __attribute__((address_space(1))) void*)(gsrc),                   \
      (__attribute__((address_space(3))) void*)(ldst), 16, 0, 0)

#define BAR() asm volatile("s_barrier" ::: "memory")
#define VMCNT(n) asm volatile("s_waitcnt vmcnt(" #n ")" ::: "memory")
#define PRIO(n) __builtin_amdgcn_s_setprio(n)

// ---------------- Kernel 1: E norms + global norm maxima ----------------
__global__ void vq_norms2(const float* __restrict__ X, const float* __restrict__ E,
                          float* __restrict__ en, unsigned* __restrict__ enmax,
                          unsigned* __restrict__ xnmax) {
  const int lane = threadIdx.x & 63;
  const int wid = threadIdx.x >> 6;
  const int nw = gridDim.x * 4;
  float emx = 0.f, xmx = 0.f;
  for (int row = blockIdx.x * 4 + wid; row < K_EMB + N_PTS; row += nw) {
    const float* src = (row < K_EMB) ? (E + (size_t)row * D_DIM)
                                     : (X + (size_t)(row - K_EMB) * D_DIM);
    float s = 0.f;
#pragma unroll
    for (int h = 0; h < 2; ++h) {
      float4 v = *(const float4*)(src + h * 256 + lane * 4);
      s += v.x * v.x + v.y * v.y + v.z * v.z + v.w * v.w;
    }
#pragma unroll
    for (int m = 32; m >= 1; m >>= 1) s += __shfl_xor(s, m);
    if (row < K_EMB) {
      if (lane == 0) en[row] = s;
      emx = fmaxf(emx, s);
    } else {
      xmx = fmaxf(xmx, s);
    }
  }
  if (lane == 0) {
    if (emx > 0.f) atomicMax(enmax, __float_as_uint(emx));
    if (xmx > 0.f) atomicMax(xnmax, __float_as_uint(xmx));
  }
}

// ---------------- Kernel 2: precompute fp16-hi tiles in MFMA-fragment order -
// Tile (mt/ct, ds) = 16KB; element (row=rg*16+l15, k=kq*8+h) at byte
// ((rg*4+kq)*16 + l15)*16 + h*2.
__global__ void vq_precvt_h(const float* __restrict__ X, const float* __restrict__ E,
                            char* __restrict__ Xpre, char* __restrict__ Epre) {
  const int bid = blockIdx.x;
  const float* src;
  char* dst;
  if (bid < 4096) {            // X: 256 mt * 16 ds
    const int mt = bid >> 4, ds = bid & 15;
    src = X + (size_t)mt * 256 * D_DIM + ds * 32;
    dst = Xpre + (size_t)bid * TILE_HB;
  } else {                     // E: 16 ct * 16 ds
    const int b = bid - 4096;
    const int ct = b >> 4, ds = b & 15;
    src = E + (size_t)ct * 256 * D_DIM + ds * 32;
    dst = Epre + (size_t)b * TILE_HB;
  }
  const int r = threadIdx.x;   // 256 threads = 256 rows
  const float* row = src + (size_t)r * D_DIM;
  const int rg = r >> 4, l15 = r & 15;
#pragma unroll
  for (int kq = 0; kq < 4; ++kq) {
    float4 a = *(const float4*)(row + kq * 8);
    float4 b = *(const float4*)(row + kq * 8 + 4);
    f16x8 H;
    H[0] = (_Float16)a.x; H[1] = (_Float16)a.y; H[2] = (_Float16)a.z; H[3] = (_Float16)a.w;
    H[4] = (_Float16)b.x; H[5] = (_Float16)b.y; H[6] = (_Float16)b.z; H[7] = (_Float16)b.w;
    *(f16x8*)(dst + ((size_t)((rg * 4 + kq) * 16 + l15)) * 16) = H;
  }
}

// ---------------- Kernel 3: hh screen GEMM + candidate emission -------------
__global__ __launch_bounds__(512, 2) void vq_screen(
    const char* __restrict__ Xpre, const char* __restrict__ Epre,
    const float* __restrict__ en, const unsigned* __restrict__ enmax,
    const unsigned* __restrict__ xnmax, unsigned* __restrict__ cnt,
    unsigned long long* __restrict__ cand) {
  __shared__ __align__(16) char bufX[2][16384];
  __shared__ __align__(16) char bufE[2][16384];
  __shared__ __align__(16) float en_lds[K_EMB];

  const int tid = threadIdx.x;
  const int lane = tid & 63;
  const int wid = tid >> 6;
  const int wm = wid >> 1;   // 0..3: 64-row group
  const int wn = wid & 1;    // 0..1: 128-col group
  const int l15 = lane & 15;
  const int lq = lane >> 4;
  const int mt = blockIdx.x;

  // deterministic screen margin (covers fp16-split truncation + denorm flush)
  const float eps = 0.004f * sqrtf(__uint_as_float(*xnmax) * __uint_as_float(*enmax)) + 0.2f;

#define STAGE_X(g1)                                                            \
  {                                                                            \
    const char* s_ = Xpre + ((size_t)(mt * 16 + ((g1) & 15))) * TILE_HB +      \
                     wid * 2048 + lane * 16;                                   \
    char* d_ = &bufX[(g1) & 1][wid * 2048];                                    \
    GLOAD16(s_, d_); GLOAD16(s_ + 1024, d_ + 1024);                            \
  }
#define STAGE_E(g1)                                                            \
  {                                                                            \
    const char* s_ = Epre + ((size_t)(g1)) * TILE_HB + wid * 2048 + lane * 16; \
    char* d_ = &bufE[(g1) & 1][wid * 2048];                                    \
    GLOAD16(s_, d_); GLOAD16(s_ + 1024, d_ + 1024);                            \
  }

  // prologue: en table + step-0 tiles; full drain + barrier (race-safe)
  {
    const char* s_ = (const char*)en + wid * 2048 + lane * 16;
    char* d_ = (char*)en_lds + wid * 2048;
    GLOAD16(s_, d_); GLOAD16(s_ + 1024, d_ + 1024);
  }
  STAGE_X(0);
  STAGE_E(0);
  VMCNT(0);
  BAR();

  f32x4 acc[4][8];
  float minv[16];
#pragma unroll
  for (int k = 0; k < 16; ++k) minv[k] = FLT_MAX;

  f16x8 AH[4], BH[8];

  for (int g = 0; g < NT; ++g) {
    const char* XB = &bufX[g & 1][0];
    const char* EB = &bufE[g & 1][0];

    if ((g & 15) == 0) {
#pragma unroll
      for (int i = 0; i < 4; ++i)
#pragma unroll
        for (int j = 0; j < 8; ++j) acc[i][j] = (f32x4)(0.f);
    }

    // ---- P1: prefetch X(g+1); counted drain; read AH + BH[0..3]; 16 MFMA ---
    if (g + 1 < NT) { STAGE_X(g + 1); VMCNT(2); } else { VMCNT(0); }
    BAR();
#pragma unroll
    for (int i = 0; i < 4; ++i)
      AH[i] = *(const f16x8*)(XB + (wm * 4 + i) * 1024 + lane * 16);
#pragma unroll
    for (int j = 0; j < 4; ++j)
      BH[j] = *(const f16x8*)(EB + (wn * 8 + j) * 1024 + lane * 16);
    PRIO(1);
#pragma unroll
    for (int i = 0; i < 4; ++i)
#pragma unroll
      for (int j = 0; j < 4; ++j)
        acc[i][j] = __builtin_amdgcn_mfma_f32_16x16x32_f16(AH[i], BH[j], acc[i][j], 0, 0, 0);
    PRIO(0);

    // ---- P2: prefetch E(g+1); read BH[4..7]; 16 MFMA ----------------------
    if (g + 1 < NT) STAGE_E(g + 1);
    BAR();
#pragma unroll
    for (int j = 4; j < 8; ++j)
      BH[j] = *(const f16x8*)(EB + (wn * 8 + j) * 1024 + lane * 16);
    PRIO(1);
#pragma unroll
    for (int i = 0; i < 4; ++i)
#pragma unroll
      for (int j = 4; j < 8; ++j)
        acc[i][j] = __builtin_amdgcn_mfma_f32_16x16x32_f16(AH[i], BH[j], acc[i][j], 0, 0, 0);
    PRIO(0);

    // ---- chunk end: row-min update + candidate emission -------------------
    if ((g & 15) == 15) {
      const int c = g >> 4;
      float ej[8];
#pragma unroll
      for (int j = 0; j < 8; ++j)
        ej[j] = en_lds[c * 256 + wn * 128 + j * 16 + l15];
#pragma unroll
      for (int k = 0; k < 16; ++k) {
        const int i = k >> 2, r = k & 3;
        float dd[8];
        float cm = FLT_MAX;
#pragma unroll
        for (int j = 0; j < 8; ++j) {
          dd[j] = fmaf(-2.f, acc[i][j][r], ej[j]);
          cm = fminf(cm, dd[j]);
        }
        // row-min across the 16 lanes holding this row's cols
#pragma unroll
        for (int m = 1; m <= 8; m <<= 1) cm = fminf(cm, __shfl_xor(cm, m));
        minv[k] = fminf(minv[k], cm);
        const float thr = minv[k] + eps;
        const int grow = mt * FBM + wm * 64 + i * 16 + lq * 4 + r;
#pragma unroll
        for (int j = 0; j < 8; ++j) {
          if (dd[j] <= thr) {
            const unsigned slot = atomicAdd(cnt, 1u);
            if (slot < CAP) {
              const int col = c * 256 + wn * 128 + j * 16 + l15;
              cand[slot] = ((unsigned long long)(unsigned)grow << 32) | (unsigned)col;
            }
          }
        }
      }
    }
  }
#undef STAGE_X
#undef STAGE_E
}

// ---------------- Kernel 4: exact fp32 refine of candidates -----------------
__global__ void vq_refine(const float* __restrict__ X, const float* __restrict__ E,
                          const float* __restrict__ en,
                          const unsigned* __restrict__ cnt,
                          const unsigned long long* __restrict__ cand,
                          unsigned long long* __restrict__ res) {
  const unsigned nc = min(*cnt, CAP);
  const int lane = threadIdx.x & 63;
  const unsigned w = blockIdx.x * (blockDim.x >> 6) + (threadIdx.x >> 6);
  const unsigned nw = gridDim.x * (blockDim.x >> 6);
  for (unsigned c = w; c < nc; c += nw) {
    const unsigned long long ent = cand[c];
    const int row = (int)(ent >> 32);
    const int col = (int)(ent & 0xffffffffu);
    const float* xp = X + (size_t)row * D_DIM + lane * 8;
    const float* ep = E + (size_t)col * D_DIM + lane * 8;
    float s = 0.f;
#pragma unroll
    for (int q = 0; q < 2; ++q) {
      const float4 xv = *(const float4*)(xp + q * 4);
      const float4 ev = *(const float4*)(ep + q * 4);
      s += xv.x * ev.x + xv.y * ev.y + xv.z * ev.z + xv.w * ev.w;
    }
#pragma unroll
    for (int m = 32; m >= 1; m >>= 1) s += __shfl_xor(s, m);
    if (lane == 0) {
      const float d = en[col] - 2.f * s + 8192.f;  // positive -> bit-monotone
      const unsigned long long pk =
          ((unsigned long long)__float_as_uint(d) << 32) | (unsigned)col;
      atomicMin(res + row, pk);  // ties -> lower col wins (np tie-break)
    }
  }
}

// ---------------- Kernel 5: gather + loss -----------------------------------
__global__ __launch_bounds__(512) void vq_gather(
    const float* __restrict__ X, const float* __restrict__ E,
    const unsigned long long* __restrict__ res, float* __restrict__ outp,
    double* __restrict__ loss_sum) {
  __shared__ float wsum[8];
  const int tid = threadIdx.x;
  const int lane = tid & 63;
  const int wid = tid >> 6;
  const int row0 = blockIdx.x * 256;
  float lsum = 0.f;
  const int sub = tid >> 7;        // 0..3
  const int c4 = (tid & 127) * 4;
  for (int r0 = 0; r0 < 256; r0 += 4) {
    const int row = row0 + r0 + sub;
    const int idx = (int)(res[row] & 0xffffffffULL);
    const float4 ev = *(const float4*)(E + (size_t)idx * D_DIM + c4);
    const float4 xv = *(const float4*)(X + (size_t)row * D_DIM + c4);
    *(float4*)(outp + (size_t)row * D_DIM + c4) = ev;
    const float dx = ev.x - xv.x, dy = ev.y - xv.y, dz = ev.z - xv.z, dw = ev.w - xv.w;
    lsum += dx * dx + dy * dy + dz * dz + dw * dw;
  }
#pragma unroll
  for (int m = 32; m >= 1; m >>= 1) lsum += __shfl_xor(lsum, m);
  if (lane == 0) wsum[wid] = lsum;
  __syncthreads();
  if (tid == 0) {
    double t = 0.0;
#pragma unroll
    for (int w = 0; w < 8; ++w) t += (double)wsum[w];
    atomicAdd(loss_sum, t);
  }
}

// ---------------- finalize loss ----------------
__global__ void vq_finalize(const double* __restrict__ loss_sum, float* __restrict__ outp) {
  if (threadIdx.x == 0 && blockIdx.x == 0) {
    outp[(size_t)N_PTS * D_DIM] =
        (float)(1.25 * (*loss_sum) / ((double)N_PTS * (double)D_DIM));
  }
}

// ================= round-2 fallback kernel (ws too small) =================
#define BM 128
#define BN 128
#define NCHUNK 32
#define BK 32
#define NSTEP 16
#define NS (NCHUNK * NSTEP)

__device__ __forceinline__ void cvt_hl(const float4 v, f16x8& H, f16x8& L, const int b) {
  _Float16 h;
  h = (_Float16)v.x; H[b + 0] = h; L[b + 0] = (_Float16)(v.x - (float)h);
  h = (_Float16)v.y; H[b + 1] = h; L[b + 1] = (_Float16)(v.y - (float)h);
  h = (_Float16)v.z; H[b + 2] = h; L[b + 2] = (_Float16)(v.z - (float)h);
  h = (_Float16)v.w; H[b + 3] = h; L[b + 3] = (_Float16)(v.w - (float)h);
}

__global__ void vq_en_only(const float* __restrict__ E, float* __restrict__ en) {
  const int wave = threadIdx.x >> 6;
  const int lane = threadIdx.x & 63;
  const int row = blockIdx.x * 4 + wave;
  const float* src = E + (size_t)row * D_DIM;
  float s = 0.f;
#pragma unroll
  for (int h = 0; h < 2; ++h) {
    float4 v = *(const float4*)(src + h * 256 + lane * 4);
    s += v.x * v.x + v.y * v.y + v.z * v.z + v.w * v.w;
  }
#pragma unroll
  for (int m = 32; m >= 1; m >>= 1) s += __shfl_xor(s, m);
  if (lane == 0) en[row] = s;
}

__global__ __launch_bounds__(256, 2) void vq_main_r2(
    const float* __restrict__ X, const float* __restrict__ E,
    const float* __restrict__ en, float* __restrict__ outp,
    double* __restrict__ loss_sum) {
  __shared__ __align__(16) _Float16 Xh[BM][BK];
  __shared__ __align__(16) _Float16 Xl[BM][BK];
  __shared__ __align__(16) _Float16 Eh[BN][BK];
  __shared__ __align__(16) _Float16 El[BN][BK];
  __shared__ float rval[2][64][2];
  __shared__ int rixd[2][64][2];
  __shared__ int fin_idx[BM];
  __shared__ float wsum[4];

  const int tid = threadIdx.x;
  const int lane = tid & 63;
  const int wid = tid >> 6;
  const int wm = wid >> 1;
  const int wn = wid & 1;
  const int l15 = lane & 15;
  const int lq = lane >> 4;
  const int row0 = blockIdx.x * BM;

  const int srow = tid >> 1;
  const int seg16 = (tid & 1) * 16;
  const float* Xbase = X + (size_t)(row0 + srow) * D_DIM + seg16;

  float4 xgA[4], egA[4], xgB[4], egB[4];
#pragma unroll
  for (int e = 0; e < 4; ++e) xgA[e] = *(const float4*)(Xbase + e * 4);
  {
    const float* ep = E + (size_t)srow * D_DIM + seg16;
#pragma unroll
    for (int e = 0; e < 4; ++e) egA[e] = *(const float4*)(ep + e * 4);
  }

  float minv[16];
  int mini[16];
#pragma unroll
  for (int k = 0; k < 16; ++k) { minv[k] = FLT_MAX; mini[k] = 0; }

  f32x4 acc[4][4];
  float enj[4];

#define STEP(S, XG, EG, XGN, EGN)                                              \
  {                                                                            \
    const int t = (S) & (NSTEP - 1);                                           \
    const int chunk = (S) >> 4;                                                \
    if (t == 0) {                                                              \
      _Pragma("unroll") for (int j = 0; j < 4; ++j)                            \
          enj[j] = en[chunk * BN + wn * 64 + j * 16 + l15];                    \
      _Pragma("unroll") for (int i = 0; i < 4; ++i)                            \
          _Pragma("unroll") for (int j = 0; j < 4; ++j)                        \
              acc[i][j] = (f32x4)(0.f);                                        \
    }                                                                          \
    __syncthreads();                                                           \
    {                                                                          \
      f16x8 H0, H1, L0, L1;                                                    \
      cvt_hl(XG[0], H0, L0, 0); cvt_hl(XG[1], H0, L0, 4);                      \
      cvt_hl(XG[2], H1, L1, 0); cvt_hl(XG[3], H1, L1, 4);                      \
      *(f16x8*)&Xh[srow][seg16] = H0;                                          \
      *(f16x8*)&Xh[srow][seg16 + 8] = H1;                                      \
      *(f16x8*)&Xl[srow][seg16] = L0;                                          \
      *(f16x8*)&Xl[srow][seg16 + 8] = L1;                                      \
      cvt_hl(EG[0], H0, L0, 0); cvt_hl(EG[1], H0, L0, 4);                      \
      cvt_hl(EG[2], H1, L1, 0); cvt_hl(EG[3], H1, L1, 4);                      \
      *(f16x8*)&Eh[srow][seg16] = H0;                                          \
      *(f16x8*)&Eh[srow][seg16 + 8] = H1;                                      \
      *(f16x8*)&El[srow][seg16] = L0;                                          \
      *(f16x8*)&El[srow][seg16 + 8] = L1;                                      \
    }                                                                          \
    if ((S) + 1 < NS) {                                                        \
      const int t1 = ((S) + 1) & (NSTEP - 1);                                  \
      const int c1 = ((S) + 1) >> 4;                                           \
      const float* xp = Xbase + t1 * BK;                                       \
      const float* ep2 = E + (size_t)(c1 * BN + srow) * D_DIM + t1 * BK + seg16; \
      _Pragma("unroll") for (int e = 0; e < 4; ++e)                            \
          XGN[e] = *(const float4*)(xp + e * 4);                               \
      _Pragma("unroll") for (int e = 0; e < 4; ++e)                            \
          EGN[e] = *(const float4*)(ep2 + e * 4);                              \
    }                                                                          \
    __syncthreads();                                                           \
    {                                                                          \
      const int qo = lq * 8;                                                   \
      f16x8 bh[4], bl[4];                                                      \
      _Pragma("unroll") for (int j = 0; j < 4; ++j) {                          \
        bh[j] = *(const f16x8*)&Eh[wn * 64 + j * 16 + l15][qo];                \
        bl[j] = *(const f16x8*)&El[wn * 64 + j * 16 + l15][qo];                \
      }                                                                        \
      _Pragma("unroll") for (int i = 0; i < 4; ++i) {                          \
        const f16x8 ah = *(const f16x8*)&Xh[wm * 64 + i * 16 + l15][qo];       \
        const f16x8 al = *(const f16x8*)&Xl[wm * 64 + i * 16 + l15][qo];       \
        _Pragma("unroll") for (int j = 0; j < 4; ++j) {                        \
          acc[i][j] = __builtin_amdgcn_mfma_f32_16x16x32_f16(ah, bh[j], acc[i][j], 0, 0, 0); \
          acc[i][j] = __builtin_amdgcn_mfma_f32_16x16x32_f16(ah, bl[j], acc[i][j], 0, 0, 0); \
          acc[i][j] = __builtin_amdgcn_mfma_f32_16x16x32_f16(al, bh[j], acc[i][j], 0, 0, 0); \
        }                                                                      \
      }                                                                        \
    }                                                                          \
    if (t == NSTEP - 1) {                                                      \
      _Pragma("unroll") for (int i = 0; i < 4; ++i)                            \
          _Pragma("unroll") for (int j = 0; j < 4; ++j) {                      \
        const int c = chunk * BN + wn * 64 + j * 16 + l15;                     \
        _Pragma("unroll") for (int r = 0; r < 4; ++r) {                        \
          const float dd = fmaf(-2.f, acc[i][j][r], enj[j]);                   \
          const int k = i * 4 + r;                                             \
          if (dd < minv[k]) { minv[k] = dd; mini[k] = c; }                     \
        }                                                                      \
      }                                                                        \
    }                                                                          \
  }

  for (int s = 0; s < NS; s += 2) {
    STEP(s, xgA, egA, xgB, egB);
    STEP(s + 1, xgB, egB, xgA, egA);
  }
#undef STEP

#pragma unroll
  for (int k = 0; k < 16; ++k) {
    float v = minv[k];
    int ix = mini[k];
#pragma unroll
    for (int m = 1; m <= 8; m <<= 1) {
      const float v2 = __shfl_xor(v, m);
      const int ix2 = __shfl_xor(ix, m);
      if (v2 < v || (v2 == v && ix2 < ix)) { v = v2; ix = ix2; }
    }
    if (l15 == 0) {
      const int lrow = (k >> 2) * 16 + lq * 4 + (k & 3);
      rval[wm][lrow][wn] = v;
      rixd[wm][lrow][wn] = ix;
    }
  }
  __syncthreads();
  if (tid < BM) {
    const int wm_ = tid >> 6, lrow = tid & 63;
    const float v0 = rval[wm_][lrow][0], v1 = rval[wm_][lrow][1];
    const int i0 = rixd[wm_][lrow][0], i1 = rixd[wm_][lrow][1];
    fin_idx[tid] = (v1 < v0 || (v1 == v0 && i1 < i0)) ? i1 : i0;
  }
  __syncthreads();

  float lsum = 0.f;
  const int half = tid >> 7;
  const int c4 = (tid & 127) * 4;
  for (int r0 = 0; r0 < BM; r0 += 2) {
    const int r = r0 + half;
    const int idx = fin_idx[r];
    const float4 ev = *(const float4*)(E + (size_t)idx * D_DIM + c4);
    const float4 xv = *(const float4*)(X + (size_t)(row0 + r) * D_DIM + c4);
    *(float4*)(outp + (size_t)(row0 + r) * D_DIM + c4) = ev;
    const float dx = ev.x - xv.x, dy = ev.y - xv.y, dz = ev.z - xv.z, dw = ev.w - xv.w;
    lsum += dx * dx + dy * dy + dz * dz + dw * dw;
  }
#pragma unroll
  for (int m = 32; m >= 1; m >>= 1) lsum += __shfl_xor(lsum, m);
  if (lane == 0) wsum[wid] = lsum;
  __syncthreads();
  if (tid == 0) {
    const double t = (double)wsum[0] + (double)wsum[1] + (double)wsum[2] + (double)wsum[3];
    atomicAdd(loss_sum, t);
  }
}

extern "C" void kernel_launch(void* const* d_in, const int* in_sizes, int n_in,
                              void* d_out, int out_size, void* d_ws, size_t ws_size,
                              hipStream_t stream) {
  const float* X = (const float*)d_in[0];
  const float* E = (const float*)d_in[1];
  float* outp = (float*)d_out;

  // ---- ws layout (fast path) ----
  const size_t off_xpre = 0;
  const size_t sz_xpre = (size_t)4096 * TILE_HB;          // 64 MB
  const size_t off_epre = off_xpre + sz_xpre;
  const size_t sz_epre = (size_t)256 * TILE_HB;           // 4 MB
  const size_t off_en = off_epre + sz_epre;               // 16 KB
  const size_t off_res = off_en + (size_t)K_EMB * 4;      // 512 KB
  const size_t off_cand = off_res + (size_t)N_PTS * 8;    // 64 MB
  const size_t off_misc = off_cand + (size_t)CAP * 8;     // 32 B
  const size_t need = off_misc + 32;

  if (ws_size >= need) {
    char* ws = (char*)d_ws;
    char* Xpre = ws + off_xpre;
    char* Epre = ws + off_epre;
    float* en = (float*)(ws + off_en);
    unsigned long long* res = (unsigned long long*)(ws + off_res);
    unsigned long long* cand = (unsigned long long*)(ws + off_cand);
    unsigned* cnt = (unsigned*)(ws + off_misc);
    unsigned* enmax = cnt + 1;
    unsigned* xnmax = cnt + 2;
    double* loss_sum = (double*)(ws + off_misc + 16);

    (void)hipMemsetAsync(ws + off_misc, 0, 32, stream);          // cnt,maxes,loss = 0
    (void)hipMemsetAsync(res, 0xFF, (size_t)N_PTS * 8, stream);  // res = +inf packed

    hipLaunchKernelGGL(vq_norms2, dim3(512), dim3(256), 0, stream, X, E, en, enmax, xnmax);
    hipLaunchKernelGGL(vq_precvt_h, dim3(4096 + 256), dim3(256), 0, stream, X, E, Xpre, Epre);
    hipLaunchKernelGGL(vq_screen, dim3(N_PTS / FBM), dim3(512), 0, stream,
                       Xpre, Epre, en, enmax, xnmax, cnt, cand);
    hipLaunchKernelGGL(vq_refine, dim3(1024), dim3(256), 0, stream,
                       X, E, en, cnt, cand, res);
    hipLaunchKernelGGL(vq_gather, dim3(N_PTS / 256), dim3(512), 0, stream,
                       X, E, res, outp, loss_sum);
    hipLaunchKernelGGL(vq_finalize, dim3(1), dim3(64), 0, stream, loss_sum, outp);
  } else {
    float* en = (float*)d_ws;
    double* loss_sum = (double*)((char*)d_ws + K_EMB * sizeof(float));

    (void)hipMemsetAsync(loss_sum, 0, sizeof(double), stream);
    hipLaunchKernelGGL(vq_en_only, dim3(K_EMB / 4), dim3(256), 0, stream, E, en);
    hipLaunchKernelGGL(vq_main_r2, dim3(N_PTS / BM), dim3(256), 0, stream,
                       X, E, en, outp, loss_sum);
    hipLaunchKernelGGL(vq_finalize, dim3(1), dim3(64), 0, stream, loss_sum, outp);
  }
}

// Round 8
// 651.227 us; speedup vs baseline: 8.5909x; 8.5909x over previous
//
#include <hip/hip_runtime.h>
#include <hip/hip_fp16.h>
#include <float.h>

typedef _Float16 f16x8 __attribute__((ext_vector_type(8)));
typedef float f32x4 __attribute__((ext_vector_type(4)));

#define N_PTS 65536
#define D_DIM 512
#define K_EMB 4096

// ---------- screen geometry ----------
#define FBM 256            // rows per block
#define FBN 256            // cols per chunk
#define NCH 16             // K_EMB / FBN
#define NDS 16             // D_DIM / 32
#define NT  256            // NCH * NDS steps
#define TILE_HB 16384      // 16KB per hi-tile (256 rows x 32 halves)
#define SLOTS 24576u       // candidate slots per block (est ~8K used)

#define GLOAD16(gsrc, ldst)                                                    \
  __builtin_amdgcn_global_load_lds(                                            \
      (const __attribute__((address_space(1))) void*)(gsrc),                   \
      (__attribute__((address_space(3))) void*)(ldst), 16, 0, 0)

#define BAR() asm volatile("s_barrier" ::: "memory")
#define VMCNT(n) asm volatile("s_waitcnt vmcnt(" #n ")" ::: "memory")
#define PRIO(n) __builtin_amdgcn_s_setprio(n)

// ---------------- Kernel 1: E norms + global norm maxima ----------------
__global__ void vq_norms2(const float* __restrict__ X, const float* __restrict__ E,
                          float* __restrict__ en, unsigned* __restrict__ enmax,
                          unsigned* __restrict__ xnmax) {
  const int lane = threadIdx.x & 63;
  const int wid = threadIdx.x >> 6;
  const int nw = gridDim.x * 4;
  float emx = 0.f, xmx = 0.f;
  for (int row = blockIdx.x * 4 + wid; row < K_EMB + N_PTS; row += nw) {
    const float* src = (row < K_EMB) ? (E + (size_t)row * D_DIM)
                                     : (X + (size_t)(row - K_EMB) * D_DIM);
    float s = 0.f;
#pragma unroll
    for (int h = 0; h < 2; ++h) {
      float4 v = *(const float4*)(src + h * 256 + lane * 4);
      s += v.x * v.x + v.y * v.y + v.z * v.z + v.w * v.w;
    }
#pragma unroll
    for (int m = 32; m >= 1; m >>= 1) s += __shfl_xor(s, m);
    if (row < K_EMB) {
      if (lane == 0) en[row] = s;
      emx = fmaxf(emx, s);
    } else {
      xmx = fmaxf(xmx, s);
    }
  }
  if (lane == 0) {
    if (emx > 0.f) atomicMax(enmax, __float_as_uint(emx));
    if (xmx > 0.f) atomicMax(xnmax, __float_as_uint(xmx));
  }
}

// ---------------- Kernel 2: precompute fp16-hi tiles in MFMA-fragment order -
__global__ void vq_precvt_h(const float* __restrict__ X, const float* __restrict__ E,
                            char* __restrict__ Xpre, char* __restrict__ Epre) {
  const int bid = blockIdx.x;
  const float* src;
  char* dst;
  if (bid < 4096) {            // X: 256 mt * 16 ds
    const int mt = bid >> 4, ds = bid & 15;
    src = X + (size_t)mt * 256 * D_DIM + ds * 32;
    dst = Xpre + (size_t)bid * TILE_HB;
  } else {                     // E: 16 ct * 16 ds
    const int b = bid - 4096;
    const int ct = b >> 4, ds = b & 15;
    src = E + (size_t)ct * 256 * D_DIM + ds * 32;
    dst = Epre + (size_t)b * TILE_HB;
  }
  const int r = threadIdx.x;   // 256 threads = 256 rows
  const float* row = src + (size_t)r * D_DIM;
  const int rg = r >> 4, l15 = r & 15;
#pragma unroll
  for (int kq = 0; kq < 4; ++kq) {
    float4 a = *(const float4*)(row + kq * 8);
    float4 b = *(const float4*)(row + kq * 8 + 4);
    f16x8 H;
    H[0] = (_Float16)a.x; H[1] = (_Float16)a.y; H[2] = (_Float16)a.z; H[3] = (_Float16)a.w;
    H[4] = (_Float16)b.x; H[5] = (_Float16)b.y; H[6] = (_Float16)b.z; H[7] = (_Float16)b.w;
    *(f16x8*)(dst + ((size_t)((rg * 4 + kq) * 16 + l15)) * 16) = H;
  }
}

// ---------------- Kernel 3: hh screen GEMM + per-block candidate emission ---
__global__ __launch_bounds__(512, 1) void vq_screen(
    const char* __restrict__ Xpre, const char* __restrict__ Epre,
    const float* __restrict__ en, const unsigned* __restrict__ enmax,
    const unsigned* __restrict__ xnmax, unsigned* __restrict__ counts,
    unsigned long long* __restrict__ cand, float* __restrict__ hhmin) {
  __shared__ __align__(16) char bufX[2][16384];
  __shared__ __align__(16) char bufE[2][16384];
  __shared__ __align__(16) float en_lds[K_EMB];
  __shared__ float argv_[2][FBM];
  __shared__ unsigned s_cnt;

  const int tid = threadIdx.x;
  const int lane = tid & 63;
  const int wid = tid >> 6;
  const int wm = wid >> 1;   // 0..3: 64-row group
  const int wn = wid & 1;    // 0..1: 128-col group
  const int l15 = lane & 15;
  const int lq = lane >> 4;
  const int mt = blockIdx.x;

  unsigned long long* myc = cand + (size_t)mt * SLOTS;
  if (tid == 0) s_cnt = 0;

  // deterministic screen margin (covers fp16-split truncation + fp32 accum)
  const float eps = 0.004f * sqrtf(__uint_as_float(*xnmax) * __uint_as_float(*enmax)) + 0.2f;

#define STAGE_X(g1)                                                            \
  {                                                                            \
    const char* s_ = Xpre + ((size_t)(mt * 16 + ((g1) & 15))) * TILE_HB +      \
                     wid * 2048 + lane * 16;                                   \
    char* d_ = &bufX[(g1) & 1][wid * 2048];                                    \
    GLOAD16(s_, d_); GLOAD16(s_ + 1024, d_ + 1024);                            \
  }
#define STAGE_E(g1)                                                            \
  {                                                                            \
    const char* s_ = Epre + ((size_t)(g1)) * TILE_HB + wid * 2048 + lane * 16; \
    char* d_ = &bufE[(g1) & 1][wid * 2048];                                    \
    GLOAD16(s_, d_); GLOAD16(s_ + 1024, d_ + 1024);                            \
  }

  // prologue: en table + step-0 tiles; full drain + barrier (race-safe; also
  // publishes s_cnt=0 to all waves)
  {
    const char* s_ = (const char*)en + wid * 2048 + lane * 16;
    char* d_ = (char*)en_lds + wid * 2048;
    GLOAD16(s_, d_); GLOAD16(s_ + 1024, d_ + 1024);
  }
  STAGE_X(0);
  STAGE_E(0);
  VMCNT(0);
  BAR();

  f32x4 acc[4][8];
  float minv[16];
#pragma unroll
  for (int k = 0; k < 16; ++k) minv[k] = FLT_MAX;

  f16x8 AH[4], BH[8];

  for (int g = 0; g < NT; ++g) {
    const char* XB = &bufX[g & 1][0];
    const char* EB = &bufE[g & 1][0];

    if ((g & 15) == 0) {
#pragma unroll
      for (int i = 0; i < 4; ++i)
#pragma unroll
        for (int j = 0; j < 8; ++j) acc[i][j] = (f32x4)(0.f);
    }

    // ---- P1: prefetch X(g+1); counted drain; read AH + BH[0..3]; 16 MFMA ---
    if (g + 1 < NT) { STAGE_X(g + 1); VMCNT(2); } else { VMCNT(0); }
    BAR();
#pragma unroll
    for (int i = 0; i < 4; ++i)
      AH[i] = *(const f16x8*)(XB + (wm * 4 + i) * 1024 + lane * 16);
#pragma unroll
    for (int j = 0; j < 4; ++j)
      BH[j] = *(const f16x8*)(EB + (wn * 8 + j) * 1024 + lane * 16);
    PRIO(1);
#pragma unroll
    for (int i = 0; i < 4; ++i)
#pragma unroll
      for (int j = 0; j < 4; ++j)
        acc[i][j] = __builtin_amdgcn_mfma_f32_16x16x32_f16(AH[i], BH[j], acc[i][j], 0, 0, 0);
    PRIO(0);

    // ---- P2: prefetch E(g+1); read BH[4..7]; 16 MFMA ----------------------
    if (g + 1 < NT) STAGE_E(g + 1);
    BAR();
#pragma unroll
    for (int j = 4; j < 8; ++j)
      BH[j] = *(const f16x8*)(EB + (wn * 8 + j) * 1024 + lane * 16);
    PRIO(1);
#pragma unroll
    for (int i = 0; i < 4; ++i)
#pragma unroll
      for (int j = 4; j < 8; ++j)
        acc[i][j] = __builtin_amdgcn_mfma_f32_16x16x32_f16(AH[i], BH[j], acc[i][j], 0, 0, 0);
    PRIO(0);

    // ---- chunk end: row-min update + candidate emission (LDS counter) -----
    if ((g & 15) == 15) {
      const int c = g >> 4;
      float ej[8];
#pragma unroll
      for (int j = 0; j < 8; ++j)
        ej[j] = en_lds[c * 256 + wn * 128 + j * 16 + l15];
#pragma unroll
      for (int k = 0; k < 16; ++k) {
        const int i = k >> 2, r = k & 3;
        float dd[8];
        float cm = FLT_MAX;
#pragma unroll
        for (int j = 0; j < 8; ++j) {
          dd[j] = fmaf(-2.f, acc[i][j][r], ej[j]);
          cm = fminf(cm, dd[j]);
        }
#pragma unroll
        for (int m = 1; m <= 8; m <<= 1) cm = fminf(cm, __shfl_xor(cm, m));
        minv[k] = fminf(minv[k], cm);
        const float thr = minv[k] + eps;
        const unsigned grow = (unsigned)(mt * FBM + wm * 64 + i * 16 + lq * 4 + r);
#pragma unroll
        for (int j = 0; j < 8; ++j) {
          if (dd[j] <= thr) {
            const unsigned slot = atomicAdd(&s_cnt, 1u);  // LDS atomic: fast
            if (slot < SLOTS) {
              const unsigned col = (unsigned)(c * 256 + wn * 128 + j * 16 + l15);
              myc[slot] = ((unsigned long long)((grow << 12) | col) << 32) |
                          __float_as_uint(dd[j]);
            }
          }
        }
      }
    }
  }
#undef STAGE_X
#undef STAGE_E

  // ---- epilogue: per-row final hh-min (across wn groups) + count ----------
#pragma unroll
  for (int k = 0; k < 16; ++k) {
    if (l15 == 0)
      argv_[wn][wm * 64 + (k >> 2) * 16 + lq * 4 + (k & 3)] = minv[k];
  }
  __syncthreads();
  if (tid < FBM)
    hhmin[mt * FBM + tid] = fminf(argv_[0][tid], argv_[1][tid]);
  if (tid == 0)
    counts[mt] = (s_cnt < SLOTS) ? s_cnt : SLOTS;
}

// ---------------- Kernel 4: filtered exact fp32 refine ----------------------
__global__ __launch_bounds__(512) void vq_refine(
    const float* __restrict__ X, const float* __restrict__ E,
    const float* __restrict__ en, const unsigned* __restrict__ enmax,
    const unsigned* __restrict__ xnmax, const unsigned* __restrict__ counts,
    const unsigned long long* __restrict__ cand, const float* __restrict__ hhmin,
    unsigned long long* __restrict__ res) {
  const int b = blockIdx.x;
  const unsigned nc = counts[b];
  const unsigned long long* myc = cand + (size_t)b * SLOTS;
  const int lane = threadIdx.x & 63;
  const int wid = threadIdx.x >> 6;
  const float eps = 0.004f * sqrtf(__uint_as_float(*xnmax) * __uint_as_float(*enmax)) + 0.2f;
  for (unsigned c = wid; c < nc; c += 8) {
    const unsigned long long ent = myc[c];
    const unsigned rc = (unsigned)(ent >> 32);
    const float dd = __uint_as_float((unsigned)(ent & 0xffffffffu));
    const unsigned grow = rc >> 12;
    const unsigned col = rc & 4095u;
    if (dd > hhmin[grow] + eps) continue;   // stale candidate (wave-uniform)
    const float* xp = X + (size_t)grow * D_DIM + lane * 8;
    const float* ep = E + (size_t)col * D_DIM + lane * 8;
    float s = 0.f;
#pragma unroll
    for (int q = 0; q < 2; ++q) {
      const float4 xv = *(const float4*)(xp + q * 4);
      const float4 ev = *(const float4*)(ep + q * 4);
      s += xv.x * ev.x + xv.y * ev.y + xv.z * ev.z + xv.w * ev.w;
    }
#pragma unroll
    for (int m = 32; m >= 1; m >>= 1) s += __shfl_xor(s, m);
    if (lane == 0) {
      const float d = en[col] - 2.f * s + 8192.f;  // positive -> bit-monotone
      const unsigned long long pk =
          ((unsigned long long)__float_as_uint(d) << 32) | col;
      atomicMin(res + grow, pk);  // ties -> lower col (np tie-break)
    }
  }
}

// ---------------- Kernel 5: gather + loss -----------------------------------
__global__ __launch_bounds__(512) void vq_gather(
    const float* __restrict__ X, const float* __restrict__ E,
    const unsigned long long* __restrict__ res, float* __restrict__ outp,
    double* __restrict__ loss_sum) {
  __shared__ float wsum[8];
  const int tid = threadIdx.x;
  const int lane = tid & 63;
  const int wid = tid >> 6;
  const int row0 = blockIdx.x * 256;
  float lsum = 0.f;
  const int sub = tid >> 7;        // 0..3
  const int c4 = (tid & 127) * 4;
  for (int r0 = 0; r0 < 256; r0 += 4) {
    const int row = row0 + r0 + sub;
    const int idx = (int)(res[row] & 0xfffULL);
    const float4 ev = *(const float4*)(E + (size_t)idx * D_DIM + c4);
    const float4 xv = *(const float4*)(X + (size_t)row * D_DIM + c4);
    *(float4*)(outp + (size_t)row * D_DIM + c4) = ev;
    const float dx = ev.x - xv.x, dy = ev.y - xv.y, dz = ev.z - xv.z, dw = ev.w - xv.w;
    lsum += dx * dx + dy * dy + dz * dz + dw * dw;
  }
#pragma unroll
  for (int m = 32; m >= 1; m >>= 1) lsum += __shfl_xor(lsum, m);
  if (lane == 0) wsum[wid] = lsum;
  __syncthreads();
  if (tid == 0) {
    double t = 0.0;
#pragma unroll
    for (int w = 0; w < 8; ++w) t += (double)wsum[w];
    atomicAdd(loss_sum, t);
  }
}

// ---------------- finalize loss ----------------
__global__ void vq_finalize(const double* __restrict__ loss_sum, float* __restrict__ outp) {
  if (threadIdx.x == 0 && blockIdx.x == 0) {
    outp[(size_t)N_PTS * D_DIM] =
        (float)(1.25 * (*loss_sum) / ((double)N_PTS * (double)D_DIM));
  }
}

// ================= round-2 fallback kernel (ws too small) =================
#define BM 128
#define BN 128
#define NCHUNK 32
#define BK 32
#define NSTEP 16
#define NS (NCHUNK * NSTEP)

__device__ __forceinline__ void cvt_hl(const float4 v, f16x8& H, f16x8& L, const int b) {
  _Float16 h;
  h = (_Float16)v.x; H[b + 0] = h; L[b + 0] = (_Float16)(v.x - (float)h);
  h = (_Float16)v.y; H[b + 1] = h; L[b + 1] = (_Float16)(v.y - (float)h);
  h = (_Float16)v.z; H[b + 2] = h; L[b + 2] = (_Float16)(v.z - (float)h);
  h = (_Float16)v.w; H[b + 3] = h; L[b + 3] = (_Float16)(v.w - (float)h);
}

__global__ void vq_en_only(const float* __restrict__ E, float* __restrict__ en) {
  const int wave = threadIdx.x >> 6;
  const int lane = threadIdx.x & 63;
  const int row = blockIdx.x * 4 + wave;
  const float* src = E + (size_t)row * D_DIM;
  float s = 0.f;
#pragma unroll
  for (int h = 0; h < 2; ++h) {
    float4 v = *(const float4*)(src + h * 256 + lane * 4);
    s += v.x * v.x + v.y * v.y + v.z * v.z + v.w * v.w;
  }
#pragma unroll
  for (int m = 32; m >= 1; m >>= 1) s += __shfl_xor(s, m);
  if (lane == 0) en[row] = s;
}

__global__ __launch_bounds__(256, 2) void vq_main_r2(
    const float* __restrict__ X, const float* __restrict__ E,
    const float* __restrict__ en, float* __restrict__ outp,
    double* __restrict__ loss_sum) {
  __shared__ __align__(16) _Float16 Xh[BM][BK];
  __shared__ __align__(16) _Float16 Xl[BM][BK];
  __shared__ __align__(16) _Float16 Eh[BN][BK];
  __shared__ __align__(16) _Float16 El[BN][BK];
  __shared__ float rval[2][64][2];
  __shared__ int rixd[2][64][2];
  __shared__ int fin_idx[BM];
  __shared__ float wsum[4];

  const int tid = threadIdx.x;
  const int lane = tid & 63;
  const int wid = tid >> 6;
  const int wm = wid >> 1;
  const int wn = wid & 1;
  const int l15 = lane & 15;
  const int lq = lane >> 4;
  const int row0 = blockIdx.x * BM;

  const int srow = tid >> 1;
  const int seg16 = (tid & 1) * 16;
  const float* Xbase = X + (size_t)(row0 + srow) * D_DIM + seg16;

  float4 xgA[4], egA[4], xgB[4], egB[4];
#pragma unroll
  for (int e = 0; e < 4; ++e) xgA[e] = *(const float4*)(Xbase + e * 4);
  {
    const float* ep = E + (size_t)srow * D_DIM + seg16;
#pragma unroll
    for (int e = 0; e < 4; ++e) egA[e] = *(const float4*)(ep + e * 4);
  }

  float minv[16];
  int mini[16];
#pragma unroll
  for (int k = 0; k < 16; ++k) { minv[k] = FLT_MAX; mini[k] = 0; }

  f32x4 acc[4][4];
  float enj[4];

#define STEP(S, XG, EG, XGN, EGN)                                              \
  {                                                                            \
    const int t = (S) & (NSTEP - 1);                                           \
    const int chunk = (S) >> 4;                                                \
    if (t == 0) {                                                              \
      _Pragma("unroll") for (int j = 0; j < 4; ++j)                            \
          enj[j] = en[chunk * BN + wn * 64 + j * 16 + l15];                    \
      _Pragma("unroll") for (int i = 0; i < 4; ++i)                            \
          _Pragma("unroll") for (int j = 0; j < 4; ++j)                        \
              acc[i][j] = (f32x4)(0.f);                                        \
    }                                                                          \
    __syncthreads();                                                           \
    {                                                                          \
      f16x8 H0, H1, L0, L1;                                                    \
      cvt_hl(XG[0], H0, L0, 0); cvt_hl(XG[1], H0, L0, 4);                      \
      cvt_hl(XG[2], H1, L1, 0); cvt_hl(XG[3], H1, L1, 4);                      \
      *(f16x8*)&Xh[srow][seg16] = H0;                                          \
      *(f16x8*)&Xh[srow][seg16 + 8] = H1;                                      \
      *(f16x8*)&Xl[srow][seg16] = L0;                                          \
      *(f16x8*)&Xl[srow][seg16 + 8] = L1;                                      \
      cvt_hl(EG[0], H0, L0, 0); cvt_hl(EG[1], H0, L0, 4);                      \
      cvt_hl(EG[2], H1, L1, 0); cvt_hl(EG[3], H1, L1, 4);                      \
      *(f16x8*)&Eh[srow][seg16] = H0;                                          \
      *(f16x8*)&Eh[srow][seg16 + 8] = H1;                                      \
      *(f16x8*)&El[srow][seg16] = L0;                                          \
      *(f16x8*)&El[srow][seg16 + 8] = L1;                                      \
    }                                                                          \
    if ((S) + 1 < NS) {                                                        \
      const int t1 = ((S) + 1) & (NSTEP - 1);                                  \
      const int c1 = ((S) + 1) >> 4;                                           \
      const float* xp = Xbase + t1 * BK;                                       \
      const float* ep2 = E + (size_t)(c1 * BN + srow) * D_DIM + t1 * BK + seg16; \
      _Pragma("unroll") for (int e = 0; e < 4; ++e)                            \
          XGN[e] = *(const float4*)(xp + e * 4);                               \
      _Pragma("unroll") for (int e = 0; e < 4; ++e)                            \
          EGN[e] = *(const float4*)(ep2 + e * 4);                              \
    }                                                                          \
    __syncthreads();                                                           \
    {                                                                          \
      const int qo = lq * 8;                                                   \
      f16x8 bh[4], bl[4];                                                      \
      _Pragma("unroll") for (int j = 0; j < 4; ++j) {                          \
        bh[j] = *(const f16x8*)&Eh[wn * 64 + j * 16 + l15][qo];                \
        bl[j] = *(const f16x8*)&El[wn * 64 + j * 16 + l15][qo];                \
      }                                                                        \
      _Pragma("unroll") for (int i = 0; i < 4; ++i) {                          \
        const f16x8 ah = *(const f16x8*)&Xh[wm * 64 + i * 16 + l15][qo];       \
        const f16x8 al = *(const f16x8*)&Xl[wm * 64 + i * 16 + l15][qo];       \
        _Pragma("unroll") for (int j = 0; j < 4; ++j) {                        \
          acc[i][j] = __builtin_amdgcn_mfma_f32_16x16x32_f16(ah, bh[j], acc[i][j], 0, 0, 0); \
          acc[i][j] = __builtin_amdgcn_mfma_f32_16x16x32_f16(ah, bl[j], acc[i][j], 0, 0, 0); \
          acc[i][j] = __builtin_amdgcn_mfma_f32_16x16x32_f16(al, bh[j], acc[i][j], 0, 0, 0); \
        }                                                                      \
      }                                                                        \
    }                                                                          \
    if (t == NSTEP - 1) {                                                      \
      _Pragma("unroll") for (int i = 0; i < 4; ++i)                            \
          _Pragma("unroll") for (int j = 0; j < 4; ++j) {                      \
        const int c = chunk * BN + wn * 64 + j * 16 + l15;                     \
        _Pragma("unroll") for (int r = 0; r < 4; ++r) {                        \
          const float dd = fmaf(-2.f, acc[i][j][r], enj[j]);                   \
          const int k = i * 4 + r;                                             \
          if (dd < minv[k]) { minv[k] = dd; mini[k] = c; }                     \
        }                                                                      \
      }                                                                        \
    }                                                                          \
  }

  for (int s = 0; s < NS; s += 2) {
    STEP(s, xgA, egA, xgB, egB);
    STEP(s + 1, xgB, egB, xgA, egA);
  }
#undef STEP

#pragma unroll
  for (int k = 0; k < 16; ++k) {
    float v = minv[k];
    int ix = mini[k];
#pragma unroll
    for (int m = 1; m <= 8; m <<= 1) {
      const float v2 = __shfl_xor(v, m);
      const int ix2 = __shfl_xor(ix, m);
      if (v2 < v || (v2 == v && ix2 < ix)) { v = v2; ix = ix2; }
    }
    if (l15 == 0) {
      const int lrow = (k >> 2) * 16 + lq * 4 + (k & 3);
      rval[wm][lrow][wn] = v;
      rixd[wm][lrow][wn] = ix;
    }
  }
  __syncthreads();
  if (tid < BM) {
    const int wm_ = tid >> 6, lrow = tid & 63;
    const float v0 = rval[wm_][lrow][0], v1 = rval[wm_][lrow][1];
    const int i0 = rixd[wm_][lrow][0], i1 = rixd[wm_][lrow][1];
    fin_idx[tid] = (v1 < v0 || (v1 == v0 && i1 < i0)) ? i1 : i0;
  }
  __syncthreads();

  float lsum = 0.f;
  const int half = tid >> 7;
  const int c4 = (tid & 127) * 4;
  for (int r0 = 0; r0 < BM; r0 += 2) {
    const int r = r0 + half;
    const int idx = fin_idx[r];
    const float4 ev = *(const float4*)(E + (size_t)idx * D_DIM + c4);
    const float4 xv = *(const float4*)(X + (size_t)(row0 + r) * D_DIM + c4);
    *(float4*)(outp + (size_t)(row0 + r) * D_DIM + c4) = ev;
    const float dx = ev.x - xv.x, dy = ev.y - xv.y, dz = ev.z - xv.z, dw = ev.w - xv.w;
    lsum += dx * dx + dy * dy + dz * dz + dw * dw;
  }
#pragma unroll
  for (int m = 32; m >= 1; m >>= 1) lsum += __shfl_xor(lsum, m);
  if (lane == 0) wsum[wid] = lsum;
  __syncthreads();
  if (tid == 0) {
    const double t = (double)wsum[0] + (double)wsum[1] + (double)wsum[2] + (double)wsum[3];
    atomicAdd(loss_sum, t);
  }
}

extern "C" void kernel_launch(void* const* d_in, const int* in_sizes, int n_in,
                              void* d_out, int out_size, void* d_ws, size_t ws_size,
                              hipStream_t stream) {
  const float* X = (const float*)d_in[0];
  const float* E = (const float*)d_in[1];
  float* outp = (float*)d_out;

  // ---- ws layout (fast path) ----
  const size_t off_xpre = 0;
  const size_t sz_xpre = (size_t)4096 * TILE_HB;            // 64 MB
  const size_t off_epre = off_xpre + sz_xpre;
  const size_t sz_epre = (size_t)256 * TILE_HB;             // 4 MB
  const size_t off_en = off_epre + sz_epre;                 // 16 KB
  const size_t off_hhmin = off_en + (size_t)K_EMB * 4;      // 256 KB
  const size_t off_res = off_hhmin + (size_t)N_PTS * 4;     // 512 KB
  const size_t off_cand = off_res + (size_t)N_PTS * 8;      // 48 MB
  const size_t off_counts = off_cand + (size_t)256 * SLOTS * 8;  // 1 KB
  const size_t off_misc = off_counts + 256 * 4;             // 32 B
  const size_t need = off_misc + 32;

  if (ws_size >= need) {
    char* ws = (char*)d_ws;
    char* Xpre = ws + off_xpre;
    char* Epre = ws + off_epre;
    float* en = (float*)(ws + off_en);
    float* hhmin = (float*)(ws + off_hhmin);
    unsigned long long* res = (unsigned long long*)(ws + off_res);
    unsigned long long* cand = (unsigned long long*)(ws + off_cand);
    unsigned* counts = (unsigned*)(ws + off_counts);
    unsigned* enmax = (unsigned*)(ws + off_misc);
    unsigned* xnmax = enmax + 1;
    double* loss_sum = (double*)(ws + off_misc + 16);

    (void)hipMemsetAsync(ws + off_misc, 0, 32, stream);          // maxes, loss = 0
    (void)hipMemsetAsync(res, 0xFF, (size_t)N_PTS * 8, stream);  // res = +inf packed

    hipLaunchKernelGGL(vq_norms2, dim3(512), dim3(256), 0, stream, X, E, en, enmax, xnmax);
    hipLaunchKernelGGL(vq_precvt_h, dim3(4096 + 256), dim3(256), 0, stream, X, E, Xpre, Epre);
    hipLaunchKernelGGL(vq_screen, dim3(N_PTS / FBM), dim3(512), 0, stream,
                       Xpre, Epre, en, enmax, xnmax, counts, cand, hhmin);
    hipLaunchKernelGGL(vq_refine, dim3(256), dim3(512), 0, stream,
                       X, E, en, enmax, xnmax, counts, cand, hhmin, res);
    hipLaunchKernelGGL(vq_gather, dim3(N_PTS / 256), dim3(512), 0, stream,
                       X, E, res, outp, loss_sum);
    hipLaunchKernelGGL(vq_finalize, dim3(1), dim3(64), 0, stream, loss_sum, outp);
  } else {
    float* en = (float*)d_ws;
    double* loss_sum = (double*)((char*)d_ws + K_EMB * sizeof(float));

    (void)hipMemsetAsync(loss_sum, 0, sizeof(double), stream);
    hipLaunchKernelGGL(vq_en_only, dim3(K_EMB / 4), dim3(256), 0, stream, E, en);
    hipLaunchKernelGGL(vq_main_r2, dim3(N_PTS / BM), dim3(256), 0, stream,
                       X, E, en, outp, loss_sum);
    hipLaunchKernelGGL(vq_finalize, dim3(1), dim3(64), 0, stream, loss_sum, outp);
  }
}